// Round 9
// baseline (226.636 us; speedup 1.0000x reference)
//
#include <hip/hip_runtime.h>
#include <cstdint>

// GIN: N=50000, D=128, E=800000, L=3.
// per layer: agg = x + gather-sum over CSR(dst); x' = relu(relu(agg@W1+b1)@W2+b2)
// CSR built once per launch. Feature math f16 (fp32 accum), MFMA GEMMs, fused MLP.
// - dst-histogram counters PADDED one-per-cache-line (cnt[n<<4]) to kill
//   per-line atomic contention (round-8 lesson: 3125 shared lines serialized).
// - atomicAdd's returned value = edge rank (packed with src into int2) ->
//   bucket pass is a single flat atomic-free scatter: ssrc[off[d]+rank] = src.
// - gather: 16 lanes/node, 3125 blocks, 8-way unrolled neighbor loop (MLP).

constexpr int N = 50000;
constexpr int D = 128;
constexpr int E = 800000;
constexpr int L = 3;
constexpr int NB_SCAN = (N + 255) / 256;  // 196
constexpr int WROW = 136;                 // padded LDS row (f16)
constexpr int CPAD = 16;                  // cnt stride (ints) = one 64B line

typedef _Float16 f16;
typedef _Float16 f16x8 __attribute__((ext_vector_type(8)));
typedef float f32x4 __attribute__((ext_vector_type(4)));

// ---- edge index load (handles int32 or int64 storage) ----
__device__ __forceinline__ bool ei_is64(const int* ei) {
  return (ei[1] == 0) && (ei[3] == 0) && (ei[5] == 0);
}
__device__ __forceinline__ int ei_src(const int* ei, int e, bool is64) {
  return is64 ? ei[2 * (size_t)e] : ei[e];
}
__device__ __forceinline__ int ei_dst(const int* ei, int e, bool is64) {
  return is64 ? ei[2 * ((size_t)E + e)] : ei[(size_t)E + e];
}

// ---------------- merged one-time prep: wprep + cvt + edge convert/hist/rank --
// grid = 384 + 3125 + 3125 = 6634 blocks, every segment exact.
__global__ __launch_bounds__(256) void k_init(const float* __restrict__ x0,
                                              const int* __restrict__ ei,
                                              const float* __restrict__ W1,
                                              const float* __restrict__ W2,
                                              f16* __restrict__ Wt,
                                              f16* __restrict__ xh,
                                              int* __restrict__ dst32,
                                              int2* __restrict__ srk,
                                              int* __restrict__ cnt) {
  const int bid = blockIdx.x;
  if (bid < 384) {
    // Wt[m][c][k] = Wsrc[m][k][c] as f16 (first L from W1, rest W2)
    int i = bid * 256 + threadIdx.x;
    int m = i >> 14;
    int c = (i >> 7) & 127;
    int k = i & 127;
    const float* src = (m < L) ? (W1 + (size_t)m * D * D)
                               : (W2 + (size_t)(m - L) * D * D);
    Wt[i] = (f16)src[(size_t)k * D + c];
  } else if (bid < 384 + 3125) {
    // x0 f32 -> xh f16, 8 elems/thread
    int i = (bid - 384) * 256 + threadIdx.x;
    float4 v0 = *(const float4*)(x0 + (size_t)i * 8);
    float4 v1 = *(const float4*)(x0 + (size_t)i * 8 + 4);
    f16x8 o = {(f16)v0.x, (f16)v0.y, (f16)v0.z, (f16)v0.w,
               (f16)v1.x, (f16)v1.y, (f16)v1.z, (f16)v1.w};
    *(f16x8*)(xh + (size_t)i * 8) = o;
  } else {
    // edge index -> int32 arrays + dst histogram; returned old count = rank.
    // cnt is padded one counter per 64B line -> no inter-node line contention.
    int e = (bid - (384 + 3125)) * 256 + threadIdx.x;
    bool is64 = ei_is64(ei);
    int s = ei_src(ei, e, is64);
    int t = ei_dst(ei, e, is64);
    dst32[e] = t;
    int r = atomicAdd(cnt + ((size_t)t << 4), 1);
    srk[e] = make_int2(s, r);
  }
}

// ---------------- scans ----------------
__global__ __launch_bounds__(256) void k_scan1(const int* __restrict__ cnt,
                                               int* __restrict__ off,
                                               int* __restrict__ bsum) {
  __shared__ int s[256];
  int i = blockIdx.x * 256 + threadIdx.x;
  int v = (i < N) ? cnt[(size_t)i << 4] : 0;
  s[threadIdx.x] = v;
  __syncthreads();
#pragma unroll
  for (int o = 1; o < 256; o <<= 1) {
    int t = (threadIdx.x >= o) ? s[threadIdx.x - o] : 0;
    __syncthreads();
    s[threadIdx.x] += t;
    __syncthreads();
  }
  if (i < N) off[i] = s[threadIdx.x] - v;
  if (threadIdx.x == 255) bsum[blockIdx.x] = s[255];
}

__global__ __launch_bounds__(256) void k_scan2(int* __restrict__ bsum) {
  __shared__ int s[256];
  int v = (threadIdx.x < NB_SCAN) ? bsum[threadIdx.x] : 0;
  s[threadIdx.x] = v;
  __syncthreads();
#pragma unroll
  for (int o = 1; o < 256; o <<= 1) {
    int t = (threadIdx.x >= o) ? s[threadIdx.x - o] : 0;
    __syncthreads();
    s[threadIdx.x] += t;
    __syncthreads();
  }
  if (threadIdx.x < NB_SCAN) bsum[threadIdx.x] = s[threadIdx.x] - v;
}

__global__ __launch_bounds__(256) void k_scan3(int* __restrict__ off,
                                               const int* __restrict__ bsum) {
  int i = blockIdx.x * 256 + threadIdx.x;
  if (i < N) off[i] += bsum[i >> 8];
  if (i == 0) off[N] = E;
}

// ---------------- bucket scatter: single flat pass, atomic-free ----------------
// ssrc[off[d] + rank] = src. Streamed dst32 + srk, cached off, scattered 4B write.
__global__ __launch_bounds__(256) void k_bucket(const int* __restrict__ dst32,
                                                const int2* __restrict__ srk,
                                                const int* __restrict__ off,
                                                int* __restrict__ ssrc) {
  int e = blockIdx.x * 256 + threadIdx.x;  // grid exact: 3125*256 = E
  int d = dst32[e];
  int2 sr = srk[e];
  ssrc[off[d] + sr.y] = sr.x;
}

// ---------------- gather-aggregate (f16): agg[n] = x[n] + sum_{j} x[src_j]
// 16 nodes/block x 16 lanes; lane owns 8 dims (16B); 8-way unrolled MLP.
__global__ __launch_bounds__(256) void k_gather_f16(const f16* __restrict__ x,
                                                    const int* __restrict__ off,
                                                    const int* __restrict__ ssrc,
                                                    f16* __restrict__ agg) {
  int n = blockIdx.x * 16 + (threadIdx.x >> 4);
  if (n >= N) return;
  const int d0 = (threadIdx.x & 15) << 3;
  f16x8 v = *(const f16x8*)(x + (size_t)n * D + d0);
  float acc[8];
#pragma unroll
  for (int j = 0; j < 8; ++j) acc[j] = (float)v[j];
  const int beg = off[n], end = off[n + 1];
  int p = beg;
  for (; p + 8 <= end; p += 8) {
    f16x8 u[8];
#pragma unroll
    for (int q = 0; q < 8; ++q) {
      int s = ssrc[p + q];
      u[q] = *(const f16x8*)(x + (size_t)s * D + d0);
    }
#pragma unroll
    for (int q = 0; q < 8; ++q)
#pragma unroll
      for (int j = 0; j < 8; ++j) acc[j] += (float)u[q][j];
  }
  if (p + 4 <= end) {
    f16x8 u[4];
#pragma unroll
    for (int q = 0; q < 4; ++q) {
      int s = ssrc[p + q];
      u[q] = *(const f16x8*)(x + (size_t)s * D + d0);
    }
#pragma unroll
    for (int q = 0; q < 4; ++q)
#pragma unroll
      for (int j = 0; j < 8; ++j) acc[j] += (float)u[q][j];
    p += 4;
  }
  for (; p < end; ++p) {
    int s = ssrc[p];
    f16x8 u = *(const f16x8*)(x + (size_t)s * D + d0);
#pragma unroll
    for (int j = 0; j < 8; ++j) acc[j] += (float)u[j];
  }
  f16x8 o;
#pragma unroll
  for (int j = 0; j < 8; ++j) o[j] = (f16)acc[j];
  *(f16x8*)(agg + (size_t)n * D + d0) = o;
}

// ---------------- fused double MFMA GEMM + bias + ReLU ----------------
// x' = relu(relu(A@W1+b1)@W2+b2). A f16 row-major; Wt* f16 [col][k].
// Block: 256 thr = 4 waves, 64 rows. h (64x128 f16) never leaves LDS.
__global__ __launch_bounds__(256) void k_gemm_fused(const f16* __restrict__ A,
                                                    const f16* __restrict__ Wt1,
                                                    const f16* __restrict__ Wt2,
                                                    const float* __restrict__ b1,
                                                    const float* __restrict__ b2,
                                                    f16* __restrict__ Ch,
                                                    float* __restrict__ Cf) {
  __shared__ f16 Ws[2][128 * WROW];
  {
    const f16x8* g1 = (const f16x8*)Wt1;
    const f16x8* g2 = (const f16x8*)Wt2;
    for (int i = threadIdx.x; i < 2048; i += 256) {
      int c = i >> 4;
      int k8 = (i & 15) << 3;
      *(f16x8*)&Ws[0][c * WROW + k8] = g1[i];
      *(f16x8*)&Ws[1][c * WROW + k8] = g2[i];
    }
  }
  __syncthreads();

  const int w = threadIdx.x >> 6;
  const int l = threadIdx.x & 63;
  const int l15 = l & 15;
  const int g = l >> 4;
  const int r0 = blockIdx.x * 64 + w * 16;

  // ---- phase A: h = relu(A @ W1 + b1) ----
  const int arow = min(r0 + l15, N - 1);
  const f16* Arow = A + (size_t)arow * D;
  f16x8 a[4];
#pragma unroll
  for (int t = 0; t < 4; ++t)
    a[t] = *(const f16x8*)(Arow + t * 32 + g * 8);

  float bc1[8], bc2[8];
#pragma unroll
  for (int c = 0; c < 8; ++c) {
    bc1[c] = b1[c * 16 + l15];
    bc2[c] = b2[c * 16 + l15];
  }

  f32x4 acc[8];
#pragma unroll
  for (int c = 0; c < 8; ++c) acc[c] = (f32x4){0.f, 0.f, 0.f, 0.f};
#pragma unroll
  for (int t = 0; t < 4; ++t) {
#pragma unroll
    for (int c = 0; c < 8; ++c) {
      f16x8 b = *(const f16x8*)&Ws[0][(c * 16 + l15) * WROW + t * 32 + g * 8];
      acc[c] = __builtin_amdgcn_mfma_f32_16x16x32_f16(a[t], b, acc[c], 0, 0, 0);
    }
  }

  __syncthreads();  // all waves done reading Ws[0]

  f16* hbuf = &Ws[0][0];
#pragma unroll
  for (int r = 0; r < 4; ++r) {
    int hr = w * 16 + g * 4 + r;
#pragma unroll
    for (int c = 0; c < 8; ++c) {
      float vv = fmaxf(acc[c][r] + bc1[c], 0.0f);
      hbuf[hr * WROW + c * 16 + l15] = (f16)vv;
    }
  }
  __syncthreads();

  // ---- phase B: x' = relu(h @ W2 + b2) ----
  f16x8 a2[4];
#pragma unroll
  for (int t = 0; t < 4; ++t)
    a2[t] = *(const f16x8*)&hbuf[(w * 16 + l15) * WROW + t * 32 + g * 8];

#pragma unroll
  for (int c = 0; c < 8; ++c) acc[c] = (f32x4){0.f, 0.f, 0.f, 0.f};
#pragma unroll
  for (int t = 0; t < 4; ++t) {
#pragma unroll
    for (int c = 0; c < 8; ++c) {
      f16x8 b = *(const f16x8*)&Ws[1][(c * 16 + l15) * WROW + t * 32 + g * 8];
      acc[c] = __builtin_amdgcn_mfma_f32_16x16x32_f16(a2[t], b, acc[c], 0, 0, 0);
    }
  }

#pragma unroll
  for (int r = 0; r < 4; ++r) {
    int rr = r0 + g * 4 + r;
    if (rr < N) {
#pragma unroll
      for (int c = 0; c < 8; ++c) {
        int col = c * 16 + l15;
        float vv = fmaxf(acc[c][r] + bc2[c], 0.0f);
        Ch[(size_t)rr * D + col] = (f16)vv;
        if (Cf) Cf[(size_t)rr * D + col] = vv;
      }
    }
  }
}

extern "C" void kernel_launch(void* const* d_in, const int* in_sizes, int n_in,
                              void* d_out, int out_size, void* d_ws, size_t ws_size,
                              hipStream_t stream) {
  const float* x0 = (const float*)d_in[0];
  const int* ei   = (const int*)d_in[1];
  const float* W1 = (const float*)d_in[2];
  const float* b1 = (const float*)d_in[3];
  const float* W2 = (const float*)d_in[4];
  const float* b2 = (const float*)d_in[5];
  float* out = (float*)d_out;

  // workspace layout (f16 arrays, then int2 (8B-aligned), then ints)
  f16* xh    = (f16*)d_ws;                          // N*D
  f16* aggh  = xh + (size_t)N * D;                  // N*D
  f16* Wt    = aggh + (size_t)N * D;                // 2*L*D*D
  int2* srk  = (int2*)(Wt + (size_t)2 * L * D * D); // E (8B aligned)
  int* dst32 = (int*)(srk + E);                     // E
  int* off   = dst32 + E;                           // N+1
  int* cnt   = off + (N + 1);                       // N*CPAD (padded counters)
  int* bsum  = cnt + (size_t)N * CPAD;              // 256
  int* ssrc  = bsum + 256;                          // E

  const dim3 blk(256);

  // ---- one-time prep ----
  hipMemsetAsync(cnt, 0, (size_t)N * CPAD * sizeof(int), stream);
  k_init<<<384 + 3125 + 3125, blk, 0, stream>>>(x0, ei, W1, W2, Wt, xh, dst32,
                                                srk, cnt);
  k_scan1<<<NB_SCAN, blk, 0, stream>>>(cnt, off, bsum);
  k_scan2<<<1, blk, 0, stream>>>(bsum);
  k_scan3<<<NB_SCAN, blk, 0, stream>>>(off, bsum);
  k_bucket<<<E / 256, blk, 0, stream>>>(dst32, srk, off, ssrc);

  const int gemm_blocks = (N + 63) / 64;  // 782
  const int gather_blocks = N / 16;       // 3125

  for (int l = 0; l < L; ++l) {
    k_gather_f16<<<gather_blocks, blk, 0, stream>>>(xh, off, ssrc, aggh);
    k_gemm_fused<<<gemm_blocks, blk, 0, stream>>>(
        aggh, Wt + (size_t)l * D * D, Wt + (size_t)(L + l) * D * D,
        b1 + (size_t)l * D, b2 + (size_t)l * D, xh,
        (l == L - 1) ? out : nullptr);
  }
}

// Round 10
// 224.458 us; speedup vs baseline: 1.0097x; 1.0097x over previous
//
#include <hip/hip_runtime.h>
#include <cstdint>

// GIN: N=50000, D=128, E=800000, L=3.
// per layer: agg = x + gather-sum over CSR(dst); x' = relu(relu(agg@W1+b1)@W2+b2)
// CSR built once per launch. Feature math f16 (fp32 accum), MFMA GEMMs, fused MLP.
// - dst-histogram uses PER-XCD COUNTER PLANES (cnt[q*N+t], q = HW XCC_ID) with
//   WORKGROUP-scope atomics -> executed in the local XCD's L2 (no sc1), 8
//   parallel atomic units instead of the memory-side device-scope unit
//   (round-9 lesson: device-scope atomics cap at ~16 line-transactions/ns).
// - rank = (q, local_rank) packed q<<29|r; scan emits offq[t*8+q] bases;
//   bucket pass stays a flat atomic-free scatter: ssrc[offq[d*8+q]+r] = src.
// - gather: 16 lanes/node, 3125 blocks, 8-way unrolled neighbor loop (MLP).

constexpr int N = 50000;
constexpr int D = 128;
constexpr int E = 800000;
constexpr int L = 3;
constexpr int NB_SCAN = (N + 255) / 256;  // 196
constexpr int WROW = 136;                 // padded LDS row (f16)

typedef _Float16 f16;
typedef _Float16 f16x8 __attribute__((ext_vector_type(8)));
typedef float f32x4 __attribute__((ext_vector_type(4)));

// ---- edge index load (handles int32 or int64 storage) ----
__device__ __forceinline__ bool ei_is64(const int* ei) {
  return (ei[1] == 0) && (ei[3] == 0) && (ei[5] == 0);
}
__device__ __forceinline__ int ei_src(const int* ei, int e, bool is64) {
  return is64 ? ei[2 * (size_t)e] : ei[e];
}
__device__ __forceinline__ int ei_dst(const int* ei, int e, bool is64) {
  return is64 ? ei[2 * ((size_t)E + e)] : ei[(size_t)E + e];
}

// ---------------- merged one-time prep: wprep + cvt + edge convert/hist/rank --
// grid = 384 + 3125 + 3125 = 6634 blocks, every segment exact.
__global__ __launch_bounds__(256) void k_init(const float* __restrict__ x0,
                                              const int* __restrict__ ei,
                                              const float* __restrict__ W1,
                                              const float* __restrict__ W2,
                                              f16* __restrict__ Wt,
                                              f16* __restrict__ xh,
                                              int* __restrict__ dst32,
                                              int2* __restrict__ srk,
                                              int* __restrict__ cnt) {
  const int bid = blockIdx.x;
  if (bid < 384) {
    // Wt[m][c][k] = Wsrc[m][k][c] as f16 (first L from W1, rest W2)
    int i = bid * 256 + threadIdx.x;
    int m = i >> 14;
    int c = (i >> 7) & 127;
    int k = i & 127;
    const float* src = (m < L) ? (W1 + (size_t)m * D * D)
                               : (W2 + (size_t)(m - L) * D * D);
    Wt[i] = (f16)src[(size_t)k * D + c];
  } else if (bid < 384 + 3125) {
    // x0 f32 -> xh f16, 8 elems/thread
    int i = (bid - 384) * 256 + threadIdx.x;
    float4 v0 = *(const float4*)(x0 + (size_t)i * 8);
    float4 v1 = *(const float4*)(x0 + (size_t)i * 8 + 4);
    f16x8 o = {(f16)v0.x, (f16)v0.y, (f16)v0.z, (f16)v0.w,
               (f16)v1.x, (f16)v1.y, (f16)v1.z, (f16)v1.w};
    *(f16x8*)(xh + (size_t)i * 8) = o;
  } else {
    // edge -> int32 + per-XCD histogram plane; L2-local atomic returns rank.
    // hwreg(HW_REG_XCC_ID=20, offset=0, size=4) -> (4-1)<<11 | 20 = 6164
    const int q = (int)(__builtin_amdgcn_s_getreg(6164)) & 7;
    int e = (bid - (384 + 3125)) * 256 + threadIdx.x;
    bool is64 = ei_is64(ei);
    int s = ei_src(ei, e, is64);
    int t = ei_dst(ei, e, is64);
    dst32[e] = t;
    // workgroup-scope -> no sc1 -> executes in this XCD's L2. Only blocks on
    // XCD q touch plane q, so L2-local atomicity is sufficient.
    int r = __hip_atomic_fetch_add(cnt + (size_t)q * N + t, 1,
                                   __ATOMIC_RELAXED, __HIP_MEMORY_SCOPE_WORKGROUP);
    srk[e] = make_int2(s, r | (q << 29));
  }
}

// ---------------- scans ----------------
// deg(i) = sum of 8 planes; block-wise exclusive scan as before.
__global__ __launch_bounds__(256) void k_scan1(const int* __restrict__ cnt,
                                               int* __restrict__ off,
                                               int* __restrict__ bsum) {
  __shared__ int s[256];
  int i = blockIdx.x * 256 + threadIdx.x;
  int v = 0;
  if (i < N) {
#pragma unroll
    for (int q = 0; q < 8; ++q) v += cnt[(size_t)q * N + i];
  }
  s[threadIdx.x] = v;
  __syncthreads();
#pragma unroll
  for (int o = 1; o < 256; o <<= 1) {
    int t = (threadIdx.x >= o) ? s[threadIdx.x - o] : 0;
    __syncthreads();
    s[threadIdx.x] += t;
    __syncthreads();
  }
  if (i < N) off[i] = s[threadIdx.x] - v;
  if (threadIdx.x == 255) bsum[blockIdx.x] = s[255];
}

__global__ __launch_bounds__(256) void k_scan2(int* __restrict__ bsum) {
  __shared__ int s[256];
  int v = (threadIdx.x < NB_SCAN) ? bsum[threadIdx.x] : 0;
  s[threadIdx.x] = v;
  __syncthreads();
#pragma unroll
  for (int o = 1; o < 256; o <<= 1) {
    int t = (threadIdx.x >= o) ? s[threadIdx.x - o] : 0;
    __syncthreads();
    s[threadIdx.x] += t;
    __syncthreads();
  }
  if (threadIdx.x < NB_SCAN) bsum[threadIdx.x] = s[threadIdx.x] - v;
}

// finalize off; emit per-(node,XCD) bases offq[i*8+q] = off[i] + prefix_q(cnt)
__global__ __launch_bounds__(256) void k_scan3(int* __restrict__ off,
                                               const int* __restrict__ bsum,
                                               const int* __restrict__ cnt,
                                               int* __restrict__ offq) {
  int i = blockIdx.x * 256 + threadIdx.x;
  if (i < N) {
    int base = off[i] + bsum[i >> 8];
    off[i] = base;
    int run = base;
#pragma unroll
    for (int q = 0; q < 8; ++q) {
      offq[(size_t)i * 8 + q] = run;
      run += cnt[(size_t)q * N + i];
    }
  }
  if (i == 0) off[N] = E;
}

// ---------------- bucket scatter: single flat pass, atomic-free ----------------
// ssrc[offq[d*8+q] + r] = src. Streamed dst32 + srk, cached offq, 4B scatter.
__global__ __launch_bounds__(256) void k_bucket(const int* __restrict__ dst32,
                                                const int2* __restrict__ srk,
                                                const int* __restrict__ offq,
                                                int* __restrict__ ssrc) {
  int e = blockIdx.x * 256 + threadIdx.x;  // grid exact: 3125*256 = E
  int d = dst32[e];
  int2 sr = srk[e];
  int q = (int)((unsigned)sr.y >> 29);
  int r = sr.y & 0x1FFFFFFF;
  ssrc[offq[(size_t)d * 8 + q] + r] = sr.x;
}

// ---------------- gather-aggregate (f16): agg[n] = x[n] + sum_{j} x[src_j]
// 16 nodes/block x 16 lanes; lane owns 8 dims (16B); 8-way unrolled MLP.
__global__ __launch_bounds__(256) void k_gather_f16(const f16* __restrict__ x,
                                                    const int* __restrict__ off,
                                                    const int* __restrict__ ssrc,
                                                    f16* __restrict__ agg) {
  int n = blockIdx.x * 16 + (threadIdx.x >> 4);
  if (n >= N) return;
  const int d0 = (threadIdx.x & 15) << 3;
  f16x8 v = *(const f16x8*)(x + (size_t)n * D + d0);
  float acc[8];
#pragma unroll
  for (int j = 0; j < 8; ++j) acc[j] = (float)v[j];
  const int beg = off[n], end = off[n + 1];
  int p = beg;
  for (; p + 8 <= end; p += 8) {
    f16x8 u[8];
#pragma unroll
    for (int q = 0; q < 8; ++q) {
      int s = ssrc[p + q];
      u[q] = *(const f16x8*)(x + (size_t)s * D + d0);
    }
#pragma unroll
    for (int q = 0; q < 8; ++q)
#pragma unroll
      for (int j = 0; j < 8; ++j) acc[j] += (float)u[q][j];
  }
  if (p + 4 <= end) {
    f16x8 u[4];
#pragma unroll
    for (int q = 0; q < 4; ++q) {
      int s = ssrc[p + q];
      u[q] = *(const f16x8*)(x + (size_t)s * D + d0);
    }
#pragma unroll
    for (int q = 0; q < 4; ++q)
#pragma unroll
      for (int j = 0; j < 8; ++j) acc[j] += (float)u[q][j];
    p += 4;
  }
  for (; p < end; ++p) {
    int s = ssrc[p];
    f16x8 u = *(const f16x8*)(x + (size_t)s * D + d0);
#pragma unroll
    for (int j = 0; j < 8; ++j) acc[j] += (float)u[j];
  }
  f16x8 o;
#pragma unroll
  for (int j = 0; j < 8; ++j) o[j] = (f16)acc[j];
  *(f16x8*)(agg + (size_t)n * D + d0) = o;
}

// ---------------- fused double MFMA GEMM + bias + ReLU ----------------
// x' = relu(relu(A@W1+b1)@W2+b2). A f16 row-major; Wt* f16 [col][k].
// Block: 256 thr = 4 waves, 64 rows. h (64x128 f16) never leaves LDS.
__global__ __launch_bounds__(256) void k_gemm_fused(const f16* __restrict__ A,
                                                    const f16* __restrict__ Wt1,
                                                    const f16* __restrict__ Wt2,
                                                    const float* __restrict__ b1,
                                                    const float* __restrict__ b2,
                                                    f16* __restrict__ Ch,
                                                    float* __restrict__ Cf) {
  __shared__ f16 Ws[2][128 * WROW];
  {
    const f16x8* g1 = (const f16x8*)Wt1;
    const f16x8* g2 = (const f16x8*)Wt2;
    for (int i = threadIdx.x; i < 2048; i += 256) {
      int c = i >> 4;
      int k8 = (i & 15) << 3;
      *(f16x8*)&Ws[0][c * WROW + k8] = g1[i];
      *(f16x8*)&Ws[1][c * WROW + k8] = g2[i];
    }
  }
  __syncthreads();

  const int w = threadIdx.x >> 6;
  const int l = threadIdx.x & 63;
  const int l15 = l & 15;
  const int g = l >> 4;
  const int r0 = blockIdx.x * 64 + w * 16;

  // ---- phase A: h = relu(A @ W1 + b1) ----
  const int arow = min(r0 + l15, N - 1);
  const f16* Arow = A + (size_t)arow * D;
  f16x8 a[4];
#pragma unroll
  for (int t = 0; t < 4; ++t)
    a[t] = *(const f16x8*)(Arow + t * 32 + g * 8);

  float bc1[8], bc2[8];
#pragma unroll
  for (int c = 0; c < 8; ++c) {
    bc1[c] = b1[c * 16 + l15];
    bc2[c] = b2[c * 16 + l15];
  }

  f32x4 acc[8];
#pragma unroll
  for (int c = 0; c < 8; ++c) acc[c] = (f32x4){0.f, 0.f, 0.f, 0.f};
#pragma unroll
  for (int t = 0; t < 4; ++t) {
#pragma unroll
    for (int c = 0; c < 8; ++c) {
      f16x8 b = *(const f16x8*)&Ws[0][(c * 16 + l15) * WROW + t * 32 + g * 8];
      acc[c] = __builtin_amdgcn_mfma_f32_16x16x32_f16(a[t], b, acc[c], 0, 0, 0);
    }
  }

  __syncthreads();  // all waves done reading Ws[0]

  f16* hbuf = &Ws[0][0];
#pragma unroll
  for (int r = 0; r < 4; ++r) {
    int hr = w * 16 + g * 4 + r;
#pragma unroll
    for (int c = 0; c < 8; ++c) {
      float vv = fmaxf(acc[c][r] + bc1[c], 0.0f);
      hbuf[hr * WROW + c * 16 + l15] = (f16)vv;
    }
  }
  __syncthreads();

  // ---- phase B: x' = relu(h @ W2 + b2) ----
  f16x8 a2[4];
#pragma unroll
  for (int t = 0; t < 4; ++t)
    a2[t] = *(const f16x8*)&hbuf[(w * 16 + l15) * WROW + t * 32 + g * 8];

#pragma unroll
  for (int c = 0; c < 8; ++c) acc[c] = (f32x4){0.f, 0.f, 0.f, 0.f};
#pragma unroll
  for (int t = 0; t < 4; ++t) {
#pragma unroll
    for (int c = 0; c < 8; ++c) {
      f16x8 b = *(const f16x8*)&Ws[1][(c * 16 + l15) * WROW + t * 32 + g * 8];
      acc[c] = __builtin_amdgcn_mfma_f32_16x16x32_f16(a2[t], b, acc[c], 0, 0, 0);
    }
  }

#pragma unroll
  for (int r = 0; r < 4; ++r) {
    int rr = r0 + g * 4 + r;
    if (rr < N) {
#pragma unroll
      for (int c = 0; c < 8; ++c) {
        int col = c * 16 + l15;
        float vv = fmaxf(acc[c][r] + bc2[c], 0.0f);
        Ch[(size_t)rr * D + col] = (f16)vv;
        if (Cf) Cf[(size_t)rr * D + col] = vv;
      }
    }
  }
}

extern "C" void kernel_launch(void* const* d_in, const int* in_sizes, int n_in,
                              void* d_out, int out_size, void* d_ws, size_t ws_size,
                              hipStream_t stream) {
  const float* x0 = (const float*)d_in[0];
  const int* ei   = (const int*)d_in[1];
  const float* W1 = (const float*)d_in[2];
  const float* b1 = (const float*)d_in[3];
  const float* W2 = (const float*)d_in[4];
  const float* b2 = (const float*)d_in[5];
  float* out = (float*)d_out;

  // workspace layout (f16 arrays, then int2 (8B-aligned), then ints)
  f16* xh    = (f16*)d_ws;                          // N*D
  f16* aggh  = xh + (size_t)N * D;                  // N*D
  f16* Wt    = aggh + (size_t)N * D;                // 2*L*D*D
  int2* srk  = (int2*)(Wt + (size_t)2 * L * D * D); // E (8B aligned)
  int* dst32 = (int*)(srk + E);                     // E
  int* off   = dst32 + E;                           // N+1
  int* cnt   = off + (N + 1);                       // 8*N (per-XCD planes)
  int* offq  = cnt + (size_t)8 * N;                 // 8*N
  int* bsum  = offq + (size_t)8 * N;                // 256
  int* ssrc  = bsum + 256;                          // E

  const dim3 blk(256);

  // ---- one-time prep ----
  hipMemsetAsync(cnt, 0, (size_t)8 * N * sizeof(int), stream);
  k_init<<<384 + 3125 + 3125, blk, 0, stream>>>(x0, ei, W1, W2, Wt, xh, dst32,
                                                srk, cnt);
  k_scan1<<<NB_SCAN, blk, 0, stream>>>(cnt, off, bsum);
  k_scan2<<<1, blk, 0, stream>>>(bsum);
  k_scan3<<<NB_SCAN, blk, 0, stream>>>(off, bsum, cnt, offq);
  k_bucket<<<E / 256, blk, 0, stream>>>(dst32, srk, offq, ssrc);

  const int gemm_blocks = (N + 63) / 64;  // 782
  const int gather_blocks = N / 16;       // 3125

  for (int l = 0; l < L; ++l) {
    k_gather_f16<<<gather_blocks, blk, 0, stream>>>(xh, off, ssrc, aggh);
    k_gemm_fused<<<gemm_blocks, blk, 0, stream>>>(
        aggh, Wt + (size_t)l * D * D, Wt + (size_t)(L + l) * D * D,
        b1 + (size_t)l * D, b2 + (size_t)l * D, xh,
        (l == L - 1) ? out : nullptr);
  }
}

// Round 11
// 193.425 us; speedup vs baseline: 1.1717x; 1.1604x over previous
//
#include <hip/hip_runtime.h>
#include <cstdint>

// GIN: N=50000, D=128, E=800000, L=3.
// per layer: agg = x + gather-sum over CSR(dst); x' = relu(relu(agg@W1+b1)@W2+b2)
// CSR built once per launch with ZERO global atomics (round 8-10 lesson:
// scattered global atomics cap at ~16 line-ops/ns regardless of scope/layout):
//   A1 (in k_init): per-block LDS 98-bin hist (bin = dst>>9) -> gcnt[p][b]
//   gbase/pscan: scans of block counts -> global bases
//   scat: LDS-ranked scatter into partition-contiguous part[] (int2 src,dst)
//   fin: per-partition (512 nodes) LDS hist+scan -> off[], windowed ssrc scatter
// Feature math f16 (fp32 accum), MFMA GEMMs, fused per-layer MLP (h in LDS).
// gather: 16 lanes/node, 3125 blocks, 8-way unrolled neighbor loop (MLP).

constexpr int N = 50000;
constexpr int D = 128;
constexpr int E = 800000;
constexpr int L = 3;
constexpr int WROW = 136;                 // padded LDS row (f16)
constexpr int PSH = 9;                    // partition shift: 512 nodes
constexpr int PN = 1 << PSH;              // 512
constexpr int K = (N + PN - 1) >> PSH;    // 98 partitions
constexpr int ABLK = 2048;                // edges per A-block
constexpr int NAB = (E + ABLK - 1) / ABLK;  // 391

typedef _Float16 f16;
typedef _Float16 f16x8 __attribute__((ext_vector_type(8)));
typedef float f32x4 __attribute__((ext_vector_type(4)));

// ---- edge index load (handles int32 or int64 storage) ----
__device__ __forceinline__ bool ei_is64(const int* ei) {
  return (ei[1] == 0) && (ei[3] == 0) && (ei[5] == 0);
}
__device__ __forceinline__ int ei_src(const int* ei, int e, bool is64) {
  return is64 ? ei[2 * (size_t)e] : ei[e];
}
__device__ __forceinline__ int ei_dst(const int* ei, int e, bool is64) {
  return is64 ? ei[2 * ((size_t)E + e)] : ei[(size_t)E + e];
}

// ---------------- merged one-time prep: wprep + cvt + edge pass A1 ----------
// grid = 384 + 3125 + 391 = 3900 blocks.
__global__ __launch_bounds__(256) void k_init(const float* __restrict__ x0,
                                              const int* __restrict__ ei,
                                              const float* __restrict__ W1,
                                              const float* __restrict__ W2,
                                              f16* __restrict__ Wt,
                                              f16* __restrict__ xh,
                                              int2* __restrict__ srcdst,
                                              int* __restrict__ gcnt) {
  __shared__ int hist[K];
  const int bid = blockIdx.x;
  if (bid < 384) {
    // Wt[m][c][k] = Wsrc[m][k][c] as f16 (first L from W1, rest W2)
    int i = bid * 256 + threadIdx.x;
    int m = i >> 14;
    int c = (i >> 7) & 127;
    int k = i & 127;
    const float* src = (m < L) ? (W1 + (size_t)m * D * D)
                               : (W2 + (size_t)(m - L) * D * D);
    Wt[i] = (f16)src[(size_t)k * D + c];
  } else if (bid < 384 + 3125) {
    // x0 f32 -> xh f16, 8 elems/thread
    int i = (bid - 384) * 256 + threadIdx.x;
    float4 v0 = *(const float4*)(x0 + (size_t)i * 8);
    float4 v1 = *(const float4*)(x0 + (size_t)i * 8 + 4);
    f16x8 o = {(f16)v0.x, (f16)v0.y, (f16)v0.z, (f16)v0.w,
               (f16)v1.x, (f16)v1.y, (f16)v1.z, (f16)v1.w};
    *(f16x8*)(xh + (size_t)i * 8) = o;
  } else {
    // edges -> int2(src,dst) + LDS partition histogram (no global atomics)
    const int b = bid - (384 + 3125);
    for (int i = threadIdx.x; i < K; i += 256) hist[i] = 0;
    __syncthreads();
    const int base = b * ABLK;
    const int nHere = min(ABLK, E - base);
    bool is64 = ei_is64(ei);
#pragma unroll
    for (int r = 0; r < ABLK / 256; ++r) {
      int idx = r * 256 + threadIdx.x;
      if (idx < nHere) {
        int e = base + idx;
        int s = ei_src(ei, e, is64);
        int d = ei_dst(ei, e, is64);
        srcdst[e] = make_int2(s, d);
        atomicAdd(&hist[d >> PSH], 1);  // LDS atomic
      }
    }
    __syncthreads();
    for (int i = threadIdx.x; i < K; i += 256) gcnt[i * NAB + b] = hist[i];
  }
}

// ---------------- per-partition prefix over block counts ----------------
// block p: exclusive prefix of gcnt[p][0..NAB-1] -> gbase; total -> psize[p]
__global__ __launch_bounds__(256) void k_gbase(const int* __restrict__ gcnt,
                                               int* __restrict__ gbase,
                                               int* __restrict__ psize) {
  __shared__ int s[256];
  __shared__ int carry;
  const int p = blockIdx.x;
  const int tid = threadIdx.x;
  if (tid == 0) carry = 0;
  __syncthreads();
  for (int chunk = 0; chunk < 2; ++chunk) {  // 2*256 >= NAB
    int i = chunk * 256 + tid;
    int v = (i < NAB) ? gcnt[p * NAB + i] : 0;
    s[tid] = v;
    __syncthreads();
#pragma unroll
    for (int o = 1; o < 256; o <<= 1) {
      int t = (tid >= o) ? s[tid - o] : 0;
      __syncthreads();
      s[tid] += t;
      __syncthreads();
    }
    int excl = s[tid] - v + carry;
    if (i < NAB) gbase[p * NAB + i] = excl;
    __syncthreads();
    if (tid == 255) carry = carry + s[255];
    __syncthreads();
  }
  if (tid == 0) psize[p] = carry;
}

// ---------------- partition base scan (K=98 values, one block) ----------------
__global__ __launch_bounds__(256) void k_pscan(const int* __restrict__ psize,
                                               int* __restrict__ pbase,
                                               int* __restrict__ off) {
  __shared__ int s[256];
  const int tid = threadIdx.x;
  int v = (tid < K) ? psize[tid] : 0;
  s[tid] = v;
  __syncthreads();
#pragma unroll
  for (int o = 1; o < 256; o <<= 1) {
    int t = (tid >= o) ? s[tid - o] : 0;
    __syncthreads();
    s[tid] += t;
    __syncthreads();
  }
  if (tid < K) pbase[tid] = s[tid] - v;
  if (tid == 0) { pbase[K] = E; off[N] = E; }
}

// ---------------- scatter edges into partition-contiguous part[] ----------------
__global__ __launch_bounds__(256) void k_scat(const int2* __restrict__ srcdst,
                                              const int* __restrict__ gbase,
                                              const int* __restrict__ pbase,
                                              int2* __restrict__ part) {
  __shared__ int rankc[K];
  const int b = blockIdx.x;
  const int tid = threadIdx.x;
  for (int i = tid; i < K; i += 256) rankc[i] = 0;
  __syncthreads();
  const int base = b * ABLK;
  const int nHere = min(ABLK, E - base);
#pragma unroll
  for (int r = 0; r < ABLK / 256; ++r) {
    int idx = r * 256 + tid;
    if (idx < nHere) {
      int2 sd = srcdst[base + idx];
      int p = sd.y >> PSH;
      int lr = atomicAdd(&rankc[p], 1);  // LDS atomic
      part[pbase[p] + gbase[p * NAB + b] + lr] = sd;
    }
  }
}

// ---------------- finalize: per-partition off[] + windowed ssrc scatter -------
__global__ __launch_bounds__(256) void k_fin(const int2* __restrict__ part,
                                             const int* __restrict__ pbase,
                                             int* __restrict__ off,
                                             int* __restrict__ ssrc) {
  __shared__ int hist[PN];
  __shared__ int bbase[PN];
  __shared__ int rc[PN];
  __shared__ int s[256];
  __shared__ int carry;
  const int p = blockIdx.x;
  const int tid = threadIdx.x;
  const int lo = p << PSH;
  const int nn = min(PN, N - lo);
  const int ebeg = pbase[p], eend = pbase[p + 1];
  for (int i = tid; i < PN; i += 256) { hist[i] = 0; rc[i] = 0; }
  if (tid == 0) carry = 0;
  __syncthreads();
  for (int e = ebeg + tid; e < eend; e += 256)
    atomicAdd(&hist[part[e].y - lo], 1);  // LDS atomic
  __syncthreads();
  // exclusive scan hist -> bbase
  for (int chunk = 0; chunk < PN / 256; ++chunk) {
    int i = chunk * 256 + tid;
    int v = hist[i];
    s[tid] = v;
    __syncthreads();
#pragma unroll
    for (int o = 1; o < 256; o <<= 1) {
      int t = (tid >= o) ? s[tid - o] : 0;
      __syncthreads();
      s[tid] += t;
      __syncthreads();
    }
    bbase[i] = s[tid] - v + carry;
    __syncthreads();
    if (tid == 255) carry = carry + s[255];
    __syncthreads();
  }
  for (int i = tid; i < nn; i += 256) off[lo + i] = ebeg + bbase[i];
  __syncthreads();
  for (int e = ebeg + tid; e < eend; e += 256) {
    int2 sd = part[e];
    int b = sd.y - lo;
    int r = atomicAdd(&rc[b], 1);  // LDS atomic
    ssrc[ebeg + bbase[b] + r] = sd.x;  // write confined to partition window
  }
}

// ---------------- gather-aggregate (f16): agg[n] = x[n] + sum_{j} x[src_j]
// 16 nodes/block x 16 lanes; lane owns 8 dims (16B); 8-way unrolled MLP.
__global__ __launch_bounds__(256) void k_gather_f16(const f16* __restrict__ x,
                                                    const int* __restrict__ off,
                                                    const int* __restrict__ ssrc,
                                                    f16* __restrict__ agg) {
  int n = blockIdx.x * 16 + (threadIdx.x >> 4);
  if (n >= N) return;
  const int d0 = (threadIdx.x & 15) << 3;
  f16x8 v = *(const f16x8*)(x + (size_t)n * D + d0);
  float acc[8];
#pragma unroll
  for (int j = 0; j < 8; ++j) acc[j] = (float)v[j];
  const int beg = off[n], end = off[n + 1];
  int p = beg;
  for (; p + 8 <= end; p += 8) {
    f16x8 u[8];
#pragma unroll
    for (int q = 0; q < 8; ++q) {
      int s = ssrc[p + q];
      u[q] = *(const f16x8*)(x + (size_t)s * D + d0);
    }
#pragma unroll
    for (int q = 0; q < 8; ++q)
#pragma unroll
      for (int j = 0; j < 8; ++j) acc[j] += (float)u[q][j];
  }
  if (p + 4 <= end) {
    f16x8 u[4];
#pragma unroll
    for (int q = 0; q < 4; ++q) {
      int s = ssrc[p + q];
      u[q] = *(const f16x8*)(x + (size_t)s * D + d0);
    }
#pragma unroll
    for (int q = 0; q < 4; ++q)
#pragma unroll
      for (int j = 0; j < 8; ++j) acc[j] += (float)u[q][j];
    p += 4;
  }
  for (; p < end; ++p) {
    int s = ssrc[p];
    f16x8 u = *(const f16x8*)(x + (size_t)s * D + d0);
#pragma unroll
    for (int j = 0; j < 8; ++j) acc[j] += (float)u[j];
  }
  f16x8 o;
#pragma unroll
  for (int j = 0; j < 8; ++j) o[j] = (f16)acc[j];
  *(f16x8*)(agg + (size_t)n * D + d0) = o;
}

// ---------------- fused double MFMA GEMM + bias + ReLU ----------------
// x' = relu(relu(A@W1+b1)@W2+b2). A f16 row-major; Wt* f16 [col][k].
// Block: 256 thr = 4 waves, 64 rows. h (64x128 f16) never leaves LDS.
__global__ __launch_bounds__(256) void k_gemm_fused(const f16* __restrict__ A,
                                                    const f16* __restrict__ Wt1,
                                                    const f16* __restrict__ Wt2,
                                                    const float* __restrict__ b1,
                                                    const float* __restrict__ b2,
                                                    f16* __restrict__ Ch,
                                                    float* __restrict__ Cf) {
  __shared__ f16 Ws[2][128 * WROW];
  {
    const f16x8* g1 = (const f16x8*)Wt1;
    const f16x8* g2 = (const f16x8*)Wt2;
    for (int i = threadIdx.x; i < 2048; i += 256) {
      int c = i >> 4;
      int k8 = (i & 15) << 3;
      *(f16x8*)&Ws[0][c * WROW + k8] = g1[i];
      *(f16x8*)&Ws[1][c * WROW + k8] = g2[i];
    }
  }
  __syncthreads();

  const int w = threadIdx.x >> 6;
  const int l = threadIdx.x & 63;
  const int l15 = l & 15;
  const int g = l >> 4;
  const int r0 = blockIdx.x * 64 + w * 16;

  // ---- phase A: h = relu(A @ W1 + b1) ----
  const int arow = min(r0 + l15, N - 1);
  const f16* Arow = A + (size_t)arow * D;
  f16x8 a[4];
#pragma unroll
  for (int t = 0; t < 4; ++t)
    a[t] = *(const f16x8*)(Arow + t * 32 + g * 8);

  float bc1[8], bc2[8];
#pragma unroll
  for (int c = 0; c < 8; ++c) {
    bc1[c] = b1[c * 16 + l15];
    bc2[c] = b2[c * 16 + l15];
  }

  f32x4 acc[8];
#pragma unroll
  for (int c = 0; c < 8; ++c) acc[c] = (f32x4){0.f, 0.f, 0.f, 0.f};
#pragma unroll
  for (int t = 0; t < 4; ++t) {
#pragma unroll
    for (int c = 0; c < 8; ++c) {
      f16x8 b = *(const f16x8*)&Ws[0][(c * 16 + l15) * WROW + t * 32 + g * 8];
      acc[c] = __builtin_amdgcn_mfma_f32_16x16x32_f16(a[t], b, acc[c], 0, 0, 0);
    }
  }

  __syncthreads();  // all waves done reading Ws[0]

  f16* hbuf = &Ws[0][0];
#pragma unroll
  for (int r = 0; r < 4; ++r) {
    int hr = w * 16 + g * 4 + r;
#pragma unroll
    for (int c = 0; c < 8; ++c) {
      float vv = fmaxf(acc[c][r] + bc1[c], 0.0f);
      hbuf[hr * WROW + c * 16 + l15] = (f16)vv;
    }
  }
  __syncthreads();

  // ---- phase B: x' = relu(h @ W2 + b2) ----
  f16x8 a2[4];
#pragma unroll
  for (int t = 0; t < 4; ++t)
    a2[t] = *(const f16x8*)&hbuf[(w * 16 + l15) * WROW + t * 32 + g * 8];

#pragma unroll
  for (int c = 0; c < 8; ++c) acc[c] = (f32x4){0.f, 0.f, 0.f, 0.f};
#pragma unroll
  for (int t = 0; t < 4; ++t) {
#pragma unroll
    for (int c = 0; c < 8; ++c) {
      f16x8 b = *(const f16x8*)&Ws[1][(c * 16 + l15) * WROW + t * 32 + g * 8];
      acc[c] = __builtin_amdgcn_mfma_f32_16x16x32_f16(a2[t], b, acc[c], 0, 0, 0);
    }
  }

#pragma unroll
  for (int r = 0; r < 4; ++r) {
    int rr = r0 + g * 4 + r;
    if (rr < N) {
#pragma unroll
      for (int c = 0; c < 8; ++c) {
        int col = c * 16 + l15;
        float vv = fmaxf(acc[c][r] + bc2[c], 0.0f);
        Ch[(size_t)rr * D + col] = (f16)vv;
        if (Cf) Cf[(size_t)rr * D + col] = vv;
      }
    }
  }
}

extern "C" void kernel_launch(void* const* d_in, const int* in_sizes, int n_in,
                              void* d_out, int out_size, void* d_ws, size_t ws_size,
                              hipStream_t stream) {
  const float* x0 = (const float*)d_in[0];
  const int* ei   = (const int*)d_in[1];
  const float* W1 = (const float*)d_in[2];
  const float* b1 = (const float*)d_in[3];
  const float* W2 = (const float*)d_in[4];
  const float* b2 = (const float*)d_in[5];
  float* out = (float*)d_out;

  // workspace layout (f16 arrays, then int2 (8B-aligned), then ints)
  f16* xh      = (f16*)d_ws;                          // N*D
  f16* aggh    = xh + (size_t)N * D;                  // N*D
  f16* Wt      = aggh + (size_t)N * D;                // 2*L*D*D
  int2* srcdst = (int2*)(Wt + (size_t)2 * L * D * D); // E (8B aligned)
  int2* part   = srcdst + E;                          // E
  int* gcnt    = (int*)(part + E);                    // K*NAB
  int* gbase   = gcnt + (size_t)K * NAB;              // K*NAB
  int* psize   = gbase + (size_t)K * NAB;             // K
  int* pbase   = psize + K;                           // K+1
  int* off     = pbase + (K + 1);                     // N+1
  int* ssrc    = off + (N + 1);                       // E

  const dim3 blk(256);

  // ---- one-time CSR build (zero global atomics) ----
  k_init<<<384 + 3125 + NAB, blk, 0, stream>>>(x0, ei, W1, W2, Wt, xh, srcdst,
                                               gcnt);
  k_gbase<<<K, blk, 0, stream>>>(gcnt, gbase, psize);
  k_pscan<<<1, blk, 0, stream>>>(psize, pbase, off);
  k_scat<<<NAB, blk, 0, stream>>>(srcdst, gbase, pbase, part);
  k_fin<<<K, blk, 0, stream>>>(part, pbase, off, ssrc);

  const int gemm_blocks = (N + 63) / 64;  // 782
  const int gather_blocks = N / 16;       // 3125

  for (int l = 0; l < L; ++l) {
    k_gather_f16<<<gather_blocks, blk, 0, stream>>>(xh, off, ssrc, aggh);
    k_gemm_fused<<<gemm_blocks, blk, 0, stream>>>(
        aggh, Wt + (size_t)l * D * D, Wt + (size_t)(L + l) * D * D,
        b1 + (size_t)l * D, b2 + (size_t)l * D, xh,
        (l == L - 1) ? out : nullptr);
  }
}